// Round 14
// baseline (88.799 us; speedup 1.0000x reference)
//
#include <hip/hip_runtime.h>
#include <hip/hip_bf16.h>

typedef __attribute__((ext_vector_type(8))) short short8;
typedef __attribute__((ext_vector_type(4))) float f32x4;
typedef __attribute__((ext_vector_type(2))) float f32x2;

#define SEPS   0.05f
#define KC     28.853900817779268f     // log2(e)/eps
#define EPSLN2 0.034657359027997264f   // eps*ln2 = 1/KC
#define LN2    0.6931471805599453f

__device__ __forceinline__ unsigned short bf16_rne(float f) {
  unsigned int u = __float_as_uint(f);
  unsigned int r = (u + 0x7fffu + ((u >> 16) & 1u)) >> 16;
  return (unsigned short)r;
}

// ---------------- K1: per-(b,m) chunk [640 c][64 x] f32 -> l2norm over c -> bf16 [64 x][640 c]
// Single-pass, register-resident; at HBM roofline (~21 us for 153 MB).
// Block 0 additionally zeroes the per-XCD work-steal counters for K2 (stream order
// guarantees all of K1 completes before K2 starts).
__global__ __launch_bounds__(1024) void norm_pack(const float* __restrict__ q,
                                                  const float* __restrict__ p,
                                                  unsigned short* __restrict__ qo,
                                                  unsigned short* __restrict__ po,
                                                  unsigned int* __restrict__ ctr) {
  int blk = blockIdx.x;
  int t = threadIdx.x;
  if (blk == 0 && t < 128) ctr[t] = 0;   // 8 counters x 16-u32 stride

  const float* src;
  unsigned short* dst;
  if (blk < 600) { src = q + (size_t)blk * 40960; dst = qo + (size_t)blk * 40960; }
  else           { src = p + (size_t)(blk - 600) * 40960; dst = po + (size_t)(blk - 600) * 40960; }

  int xg = t & 15, cg = t >> 4;   // xg: x-quad 0..15, cg: c-row 0..63
  int x4 = xg * 4;

  f32x4 v[10];
  float ss[4] = {0.f, 0.f, 0.f, 0.f};
  #pragma unroll
  for (int k = 0; k < 10; ++k) {
    v[k] = *(const f32x4*)(src + (size_t)(cg + 64 * k) * 64 + x4);
    #pragma unroll
    for (int j = 0; j < 4; ++j) ss[j] = fmaf(v[k][j], v[k][j], ss[j]);
  }

  #pragma unroll
  for (int j = 0; j < 4; ++j) {
    ss[j] += __shfl_xor(ss[j], 16, 64);
    ss[j] += __shfl_xor(ss[j], 32, 64);
  }
  __shared__ float red[16][64];
  __shared__ float scale_s[64];
  int wv = t >> 6, ln = t & 63;
  if (ln < 16) {
    #pragma unroll
    for (int j = 0; j < 4; ++j) red[wv][ln * 4 + j] = ss[j];
  }
  __syncthreads();
  if (t < 64) {
    float s = 0.f;
    #pragma unroll
    for (int w2 = 0; w2 < 16; ++w2) s += red[w2][t];
    scale_s[t] = 1.0f / fmaxf(sqrtf(s), 1e-12f);  // matches x/max(||x||,eps)
  }
  __syncthreads();
  float sc[4];
  #pragma unroll
  for (int j = 0; j < 4; ++j) sc[j] = scale_s[x4 + j];

  __shared__ float tile[2][64][65];
  int t9 = t & 511, th = t >> 9;
  int pr = t9 >> 3, pc = (t9 & 7) * 8;
  #pragma unroll
  for (int rd = 0; rd < 5; ++rd) {
    #pragma unroll
    for (int h = 0; h < 2; ++h) {
      f32x4 u = v[rd * 2 + h];
      #pragma unroll
      for (int j = 0; j < 4; ++j) tile[h][x4 + j][cg] = u[j] * sc[j];
    }
    __syncthreads();
    unsigned int pk[4];
    #pragma unroll
    for (int k2 = 0; k2 < 4; ++k2) {
      unsigned int lo = bf16_rne(tile[th][pr][pc + 2 * k2]);
      unsigned int hi = bf16_rne(tile[th][pr][pc + 2 * k2 + 1]);
      pk[k2] = lo | (hi << 16);
    }
    *(uint4*)(dst + (size_t)pr * 640 + (rd * 2 + th) * 64 + pc) = make_uint4(pk[0], pk[1], pk[2], pk[3]);
    __syncthreads();
  }
}

// ---------------- K2: fused per-(b,q,w) {GEMM -> Sinkhorn -> logit}, 8 KB LDS, (64,2),
// PERSISTENT: 2048 blocks = exact chip residency (8 waves/CU); XCD x owns problems
// [375x, 375x+375) (keeps round-12's L2 grouping win); per-XCD atomic counter feeds
// blocks ~1.46 problems each. Kills round-13's measured 27% serial-tail (11.72
// blocks/CU work vs 8 resident -> occupancy 16.6% of 25% peak). Aitken reverted
// (round-13: neutral-negative; exit fires ~iter 14-18). Per-problem math identical
// to round 12.
__device__ __forceinline__ float rl(float v, int lane) {
  return __int_as_float(__builtin_amdgcn_readlane(__float_as_int(v), lane));
}
__device__ __forceinline__ long pack2(float v, int j) {
  unsigned int lo = (unsigned int)__builtin_amdgcn_readlane(__float_as_int(v), j);
  unsigned int hi = (unsigned int)__builtin_amdgcn_readlane(__float_as_int(v), j + 1);
  return (long)(((unsigned long long)hi << 32) | lo);
}
__device__ __forceinline__ float wredsum(float v) {
  #pragma unroll
  for (int m = 1; m < 64; m <<= 1) v += __shfl_xor(v, m, 64);
  return v;
}
#define SWZ(row) ((((row) ^ ((row) >> 3)) & 15) << 2)

__global__ __launch_bounds__(64, 2) void gemm_sink(const unsigned short* __restrict__ A,
                                                   const unsigned short* __restrict__ B,
                                                   float* __restrict__ out,
                                                   unsigned int* __restrict__ ctr) {
  __shared__ alignas(16) char sh[8192];
  unsigned short (*As)[64][32] = (unsigned short (*)[64][32])sh;  // [2][64][32] = 8 KB
  float* Cm = (float*)sh;  // 2048 f32 = one 32-row chunk, reused after GEMM phase

  int xcd = blockIdx.x & 7;
  unsigned int* myctr = ctr + xcd * 16;   // 64B-strided per-XCD counters

  int l = threadIdx.x;
  int lrow = l >> 2, lslot = l & 3;
  int fr = l & 15, k8 = l >> 4;
  int soff = ((k8 ^ (fr & 3)) << 4);  // swizzled 16B slot byte offset within 64B row

  #pragma unroll 1
  for (;;) {
    unsigned int myid = 0;
    if (l == 0) myid = atomicAdd(myctr, 1u);
    myid = (unsigned int)__shfl((int)myid, 0, 64);
    if (myid >= 375u) break;

    int blk = xcd * 375 + (int)myid;
    int w = blk % 5;
    int bq = blk / 5;
    int b = bq / 75;
    const unsigned short* Ab = A + (size_t)bq * 40960;
    const unsigned short* Bb = B + (size_t)(b * 5 + w) * 40960;

    f32x4 acc[4][4];
    #pragma unroll
    for (int i = 0; i < 4; ++i)
      #pragma unroll
      for (int j = 0; j < 4; ++j)
        acc[i][j] = (f32x4){0.f, 0.f, 0.f, 0.f};

    auto stageA = [&](int buf, int k0) {
      #pragma unroll
      for (int t = 0; t < 4; ++t) {
        int row = t * 16 + lrow;
        int sl = lslot ^ (row & 3);
        __builtin_amdgcn_global_load_lds(
            (const __attribute__((address_space(1))) unsigned int*)(Ab + (size_t)row * 640 + k0 + sl * 8),
            (__attribute__((address_space(3))) unsigned int*)&As[buf][t * 16][0], 16, 0, 0);
      }
    };
    short8 bF0[4], bF1[4];
    auto loadB = [&](short8* dst, int k0) {
      #pragma unroll
      for (int mi = 0; mi < 4; ++mi)
        dst[mi] = *(const short8*)(Bb + (size_t)(mi * 16 + fr) * 640 + k0 + k8 * 8);
    };
    auto compute = [&](int buf, const short8* bFr) {
      short8 aF[4];
      #pragma unroll
      for (int mi = 0; mi < 4; ++mi)
        aF[mi] = *(const short8*)((const char*)&As[buf][0][0] + ((mi * 16 + fr) * 64 + soff));
      #pragma unroll
      for (int mi = 0; mi < 4; ++mi)
        #pragma unroll
        for (int ni = 0; ni < 4; ++ni)
          acc[mi][ni] = __builtin_amdgcn_mfma_f32_16x16x32_bf16(aF[mi], bFr[ni], acc[mi][ni], 0, 0, 0);
    };

    stageA(0, 0);
    loadB(bF0, 0);
    #pragma unroll 1
    for (int s2 = 0; s2 < 10; ++s2) {
      int se = s2 * 2;                          // even step: As[0], bF0
      stageA(1, (se + 1) * 32);                 // se <= 18 -> always a next step
      loadB(bF1, (se + 1) * 32);
      asm volatile("s_waitcnt vmcnt(8)" ::: "memory");   // step-se's A stage + B regs done
      compute(0, bF0);
      int so = se + 1;                          // odd step: As[1], bF1
      if (so < 19) {
        stageA(0, (so + 1) * 32);
        loadB(bF0, (so + 1) * 32);
        asm volatile("s_waitcnt vmcnt(8)" ::: "memory");
      } else {
        asm volatile("s_waitcnt vmcnt(0)" ::: "memory");
      }
      compute(1, bF1);
    }

    // ---- transition: cost = 1 - sim through TWO 32-row chunks of Cm (8 KB each),
    // overlaying the staging LDS. Single wave: DS pipe in-order; lgkmcnt(0)+sched_barrier
    // pins the write->read and read->overwrite boundaries.
    // C/D layout: acc[mi][ni][r] = C[row = mi*16 + k8*4 + r][col = ni*16 + fr].
    f32x2 EcolP[32], ErowP[32];
    float colsum = 0.f, rowsum = 0.f;
    #pragma unroll
    for (int ch = 0; ch < 2; ++ch) {
      #pragma unroll
      for (int mh = 0; mh < 2; ++mh) {
        int mi = ch * 2 + mh;
        #pragma unroll
        for (int ni = 0; ni < 4; ++ni)
          #pragma unroll
          for (int r = 0; r < 4; ++r) {
            int rr = mh * 16 + k8 * 4 + r;       // local row 0..31
            int col = ni * 16 + fr;
            Cm[rr * 64 + (col ^ SWZ(rr))] = 1.0f - acc[mi][ni][r];
          }
      }
      asm volatile("s_waitcnt lgkmcnt(0)" ::: "memory");
      __builtin_amdgcn_sched_barrier(0);
      // Ecol slice: lane l reads column l of this chunk (l^SWZ permutes within row: 2-way)
      #pragma unroll
      for (int i2 = 0; i2 < 16; ++i2) {
        float c0 = Cm[(2 * i2) * 64 + (l ^ SWZ(2 * i2))];
        float c1 = Cm[(2 * i2 + 1) * 64 + (l ^ SWZ(2 * i2 + 1))];
        colsum += (1.0f - c0);
        colsum += (1.0f - c1);
        EcolP[ch * 16 + i2][0] = __builtin_amdgcn_exp2f(-KC * c0);
        EcolP[ch * 16 + i2][1] = __builtin_amdgcn_exp2f(-KC * c1);
      }
      // Erow slice: the 32 lanes whose row lives in this chunk grab it (f32x4; SWZ is a
      // multiple of 4 words so 16B chunks stay contiguous).
      if ((l >> 5) == ch) {
        int rr = l & 31, sw = SWZ(rr);
        #pragma unroll
        for (int j4 = 0; j4 < 16; ++j4) {
          f32x4 cc = *(const f32x4*)&Cm[rr * 64 + ((j4 * 4) ^ sw)];
          rowsum += cc[0]; rowsum += cc[1]; rowsum += cc[2]; rowsum += cc[3];
          ErowP[j4 * 2][0]     = __builtin_amdgcn_exp2f(-KC * cc[0]);
          ErowP[j4 * 2][1]     = __builtin_amdgcn_exp2f(-KC * cc[1]);
          ErowP[j4 * 2 + 1][0] = __builtin_amdgcn_exp2f(-KC * cc[2]);
          ErowP[j4 * 2 + 1][1] = __builtin_amdgcn_exp2f(-KC * cc[3]);
        }
      }
      asm volatile("s_waitcnt lgkmcnt(0)" ::: "memory");
      __builtin_amdgcn_sched_barrier(0);
    }

    // masses: weight_1 = relu(mean_y sim)+1e-3 (rows), weight_2' = relu(mean_x sim)+1e-3 (cols)
    float w1 = fmaxf(1.0f - rowsum * (1.0f / 64.0f), 0.f) + 0.001f;
    float w2 = fmaxf(colsum * (1.0f / 64.0f), 0.f) + 0.001f;
    float amass = w1 * __builtin_amdgcn_rcpf(wredsum(w1));
    float bmass = w2 * __builtin_amdgcn_rcpf(wredsum(w2));

    const float UMIN = 1.80485139e-35f;   // exp(-80) == exp(-4/eps): the f,g +-4 clamp
    const float UMAX = 5.54062238e+34f;   // exp(+80)

    float uu = 0.f, vv = 1.0f;            // g0 = 0 -> v0 = 1
    float pv = vv;                        // convergence window anchor
    #pragma unroll 1
    for (int it = 0; it < 50; ++it) {
      // u-update: s_l = sum_j Erow[j] * v_j, SGPR-batched broadcast + 4 pk chains
      f32x2 sA0 = {1e-37f, 0.f}, sA1 = {0.f, 0.f}, sA2 = {0.f, 0.f}, sA3 = {0.f, 0.f};
      #pragma unroll
      for (int g = 0; g < 4; ++g) {
        long P[8];
        #pragma unroll
        for (int p = 0; p < 8; ++p) P[p] = pack2(vv, (g * 8 + p) * 2);
        #pragma unroll
        for (int p = 0; p < 8; ++p) {
          if ((p & 3) == 0)      asm("v_pk_fma_f32 %0, %1, %2, %0" : "+v"(sA0) : "v"(ErowP[g * 8 + p]), "s"(P[p]));
          else if ((p & 3) == 1) asm("v_pk_fma_f32 %0, %1, %2, %0" : "+v"(sA1) : "v"(ErowP[g * 8 + p]), "s"(P[p]));
          else if ((p & 3) == 2) asm("v_pk_fma_f32 %0, %1, %2, %0" : "+v"(sA2) : "v"(ErowP[g * 8 + p]), "s"(P[p]));
          else                   asm("v_pk_fma_f32 %0, %1, %2, %0" : "+v"(sA3) : "v"(ErowP[g * 8 + p]), "s"(P[p]));
        }
      }
      float s = ((sA0[0] + sA0[1]) + (sA1[0] + sA1[1])) + ((sA2[0] + sA2[1]) + (sA3[0] + sA3[1]));
      uu = fminf(fmaxf(amass * __builtin_amdgcn_rcpf(s), UMIN), UMAX);

      // v-update: t_l = sum_i Ecol[i] * u_i
      f32x2 tA0 = {1e-37f, 0.f}, tA1 = {0.f, 0.f}, tA2 = {0.f, 0.f}, tA3 = {0.f, 0.f};
      #pragma unroll
      for (int g = 0; g < 4; ++g) {
        long P[8];
        #pragma unroll
        for (int p = 0; p < 8; ++p) P[p] = pack2(uu, (g * 8 + p) * 2);
        #pragma unroll
        for (int p = 0; p < 8; ++p) {
          if ((p & 3) == 0)      asm("v_pk_fma_f32 %0, %1, %2, %0" : "+v"(tA0) : "v"(EcolP[g * 8 + p]), "s"(P[p]));
          else if ((p & 3) == 1) asm("v_pk_fma_f32 %0, %1, %2, %0" : "+v"(tA1) : "v"(EcolP[g * 8 + p]), "s"(P[p]));
          else if ((p & 3) == 2) asm("v_pk_fma_f32 %0, %1, %2, %0" : "+v"(tA2) : "v"(EcolP[g * 8 + p]), "s"(P[p]));
          else                   asm("v_pk_fma_f32 %0, %1, %2, %0" : "+v"(tA3) : "v"(EcolP[g * 8 + p]), "s"(P[p]));
        }
      }
      float t = ((tA0[0] + tA0[1]) + (tA1[0] + tA1[1])) + ((tA2[0] + tA2[1]) + (tA3[0] + tA3[1]));
      vv = fminf(fmaxf(bmass * __builtin_amdgcn_rcpf(t), UMIN), UMAX);

      // fixed-point early-exit: converged-to-1e-6 iterates drift <1e-5 on logits vs iter-50
      if ((it & 1) == 1) {
        if (__all(fabsf(vv - pv) <= 1e-6f * vv)) break;
        pv = vv;
      }
    }

    // logits = 12.5 * sum_ij (1 - c_ij) * u_i v_j E_ij ; recover c = -eps*ln2*log2(E)
    float a1 = 0.f, a2 = 0.f;
    #pragma unroll
    for (int j = 0; j < 64; ++j) {
      float Ej = ErowP[j >> 1][j & 1];
      float e = fminf((uu * Ej) * rl(vv, j), 1.32922800e36f);  // 2^120 guard parity
      float c = -EPSLN2 * __builtin_amdgcn_logf(Ej);
      a1 += e;
      a2 = fmaf(c, e, a2);
    }
    float tot = wredsum(a1 - a2);
    if (l == 0) out[blk] = 12.5f * tot;
  }
}

extern "C" void kernel_launch(void* const* d_in, const int* in_sizes, int n_in,
                              void* d_out, int out_size, void* d_ws, size_t ws_size,
                              hipStream_t stream) {
  const float* query = (const float*)d_in[0];
  const float* proto = (const float*)d_in[1];
  float* out = (float*)d_out;
  char* ws = (char*)d_ws;

  const size_t A_OFF = 0;                  // 8*75*64*640*2  = 49,152,000
  const size_t B_OFF = 49152000;           // 8*5*64*640*2   =  3,276,800
  const size_t C_OFF = 52428800;           // 8 x 16 u32 work-steal counters (512 B)
  if (ws_size < 52429312ull) return;       // loud failure rather than OOB

  unsigned short* Abf = (unsigned short*)(ws + A_OFF);
  unsigned short* Bbf = (unsigned short*)(ws + B_OFF);
  unsigned int* ctr = (unsigned int*)(ws + C_OFF);

  norm_pack<<<640, 1024, 0, stream>>>(query, proto, Abf, Bbf, ctr);  // + counter zeroing
  gemm_sink<<<2048, 64, 0, stream>>>(Abf, Bbf, out, ctr);            // persistent, work-stealing
}

// Round 15
// 84.510 us; speedup vs baseline: 1.0508x; 1.0508x over previous
//
#include <hip/hip_runtime.h>
#include <hip/hip_bf16.h>

typedef __attribute__((ext_vector_type(8))) short short8;
typedef __attribute__((ext_vector_type(4))) float f32x4;
typedef __attribute__((ext_vector_type(2))) float f32x2;

#define SEPS   0.05f
#define KC     28.853900817779268f     // log2(e)/eps
#define EPSLN2 0.034657359027997264f   // eps*ln2 = 1/KC
#define LN2    0.6931471805599453f

__device__ __forceinline__ unsigned short bf16_rne(float f) {
  unsigned int u = __float_as_uint(f);
  unsigned int r = (u + 0x7fffu + ((u >> 16) & 1u)) >> 16;
  return (unsigned short)r;
}

// ---------------- K1: per-(b,m) chunk [640 c][64 x] f32 -> l2norm over c -> bf16 [64 x][640 c]
// Single-pass, register-resident; at HBM roofline (~21 us for 153 MB).
// Block 0 additionally zeroes the per-XCD work-steal counters for K2 (stream order
// guarantees all of K1 completes before K2 starts).
__global__ __launch_bounds__(1024) void norm_pack(const float* __restrict__ q,
                                                  const float* __restrict__ p,
                                                  unsigned short* __restrict__ qo,
                                                  unsigned short* __restrict__ po,
                                                  unsigned int* __restrict__ ctr) {
  int blk = blockIdx.x;
  int t = threadIdx.x;
  if (blk == 0 && t < 128) ctr[t] = 0;   // 8 counters x 16-u32 stride

  const float* src;
  unsigned short* dst;
  if (blk < 600) { src = q + (size_t)blk * 40960; dst = qo + (size_t)blk * 40960; }
  else           { src = p + (size_t)(blk - 600) * 40960; dst = po + (size_t)(blk - 600) * 40960; }

  int xg = t & 15, cg = t >> 4;   // xg: x-quad 0..15, cg: c-row 0..63
  int x4 = xg * 4;

  f32x4 v[10];
  float ss[4] = {0.f, 0.f, 0.f, 0.f};
  #pragma unroll
  for (int k = 0; k < 10; ++k) {
    v[k] = *(const f32x4*)(src + (size_t)(cg + 64 * k) * 64 + x4);
    #pragma unroll
    for (int j = 0; j < 4; ++j) ss[j] = fmaf(v[k][j], v[k][j], ss[j]);
  }

  #pragma unroll
  for (int j = 0; j < 4; ++j) {
    ss[j] += __shfl_xor(ss[j], 16, 64);
    ss[j] += __shfl_xor(ss[j], 32, 64);
  }
  __shared__ float red[16][64];
  __shared__ float scale_s[64];
  int wv = t >> 6, ln = t & 63;
  if (ln < 16) {
    #pragma unroll
    for (int j = 0; j < 4; ++j) red[wv][ln * 4 + j] = ss[j];
  }
  __syncthreads();
  if (t < 64) {
    float s = 0.f;
    #pragma unroll
    for (int w2 = 0; w2 < 16; ++w2) s += red[w2][t];
    scale_s[t] = 1.0f / fmaxf(sqrtf(s), 1e-12f);  // matches x/max(||x||,eps)
  }
  __syncthreads();
  float sc[4];
  #pragma unroll
  for (int j = 0; j < 4; ++j) sc[j] = scale_s[x4 + j];

  __shared__ float tile[2][64][65];
  int t9 = t & 511, th = t >> 9;
  int pr = t9 >> 3, pc = (t9 & 7) * 8;
  #pragma unroll
  for (int rd = 0; rd < 5; ++rd) {
    #pragma unroll
    for (int h = 0; h < 2; ++h) {
      f32x4 u = v[rd * 2 + h];
      #pragma unroll
      for (int j = 0; j < 4; ++j) tile[h][x4 + j][cg] = u[j] * sc[j];
    }
    __syncthreads();
    unsigned int pk[4];
    #pragma unroll
    for (int k2 = 0; k2 < 4; ++k2) {
      unsigned int lo = bf16_rne(tile[th][pr][pc + 2 * k2]);
      unsigned int hi = bf16_rne(tile[th][pr][pc + 2 * k2 + 1]);
      pk[k2] = lo | (hi << 16);
    }
    *(uint4*)(dst + (size_t)pr * 640 + (rd * 2 + th) * 64 + pc) = make_uint4(pk[0], pk[1], pk[2], pk[3]);
    __syncthreads();
  }
}

// ---------------- K2: fused per-(b,q,w) {GEMM -> Sinkhorn -> logit}, 8 KB LDS, (64,2),
// PERSISTENT work-stealing, SCALARIZED: round-14's regression was the __shfl-broadcast
// work id living in a VGPR -> compiler lost wave-uniformity of blk/Ab/Bb -> all base
// addresses became per-lane VGPR pairs (+32 VGPR, 3.7 MB scratch). Fix: broadcast via
// readfirstlane (SGPR result, architecturally uniform) so addressing stays scalar,
// identical to the static round-13 codegen. 2048 blocks = exact residency; per-XCD
// counters keep round-12's L2 grouping; kills the measured ~27% serial tail.
__device__ __forceinline__ float rl(float v, int lane) {
  return __int_as_float(__builtin_amdgcn_readlane(__float_as_int(v), lane));
}
__device__ __forceinline__ long pack2(float v, int j) {
  unsigned int lo = (unsigned int)__builtin_amdgcn_readlane(__float_as_int(v), j);
  unsigned int hi = (unsigned int)__builtin_amdgcn_readlane(__float_as_int(v), j + 1);
  return (long)(((unsigned long long)hi << 32) | lo);
}
__device__ __forceinline__ float wredsum(float v) {
  #pragma unroll
  for (int m = 1; m < 64; m <<= 1) v += __shfl_xor(v, m, 64);
  return v;
}
#define SWZ(row) ((((row) ^ ((row) >> 3)) & 15) << 2)

__global__ __launch_bounds__(64, 2) void gemm_sink(const unsigned short* __restrict__ A,
                                                   const unsigned short* __restrict__ B,
                                                   float* __restrict__ out,
                                                   unsigned int* __restrict__ ctr) {
  __shared__ alignas(16) char sh[8192];
  unsigned short (*As)[64][32] = (unsigned short (*)[64][32])sh;  // [2][64][32] = 8 KB
  float* Cm = (float*)sh;  // 2048 f32 = one 32-row chunk, reused after GEMM phase

  int xcd = blockIdx.x & 7;
  unsigned int* myctr = ctr + xcd * 16;   // 64B-strided per-XCD counters

  int l = threadIdx.x;
  int lrow = l >> 2, lslot = l & 3;
  int fr = l & 15, k8 = l >> 4;
  int soff = ((k8 ^ (fr & 3)) << 4);  // swizzled 16B slot byte offset within 64B row

  #pragma unroll 1
  for (;;) {
    unsigned int tmp = 0;
    if (l == 0) tmp = atomicAdd(myctr, 1u);
    int myid = (int)__builtin_amdgcn_readfirstlane((int)tmp);  // SGPR: wave-uniform
    if (myid >= 375) break;

    int blk = xcd * 375 + myid;
    int w = blk % 5;
    int bq = blk / 5;
    int b = bq / 75;
    const unsigned short* Ab = A + (size_t)bq * 40960;
    const unsigned short* Bb = B + (size_t)(b * 5 + w) * 40960;

    f32x4 acc[4][4];
    #pragma unroll
    for (int i = 0; i < 4; ++i)
      #pragma unroll
      for (int j = 0; j < 4; ++j)
        acc[i][j] = (f32x4){0.f, 0.f, 0.f, 0.f};

    auto stageA = [&](int buf, int k0) {
      #pragma unroll
      for (int t = 0; t < 4; ++t) {
        int row = t * 16 + lrow;
        int sl = lslot ^ (row & 3);
        __builtin_amdgcn_global_load_lds(
            (const __attribute__((address_space(1))) unsigned int*)(Ab + (size_t)row * 640 + k0 + sl * 8),
            (__attribute__((address_space(3))) unsigned int*)&As[buf][t * 16][0], 16, 0, 0);
      }
    };
    short8 bF0[4], bF1[4];
    auto loadB = [&](short8* dst, int k0) {
      #pragma unroll
      for (int mi = 0; mi < 4; ++mi)
        dst[mi] = *(const short8*)(Bb + (size_t)(mi * 16 + fr) * 640 + k0 + k8 * 8);
    };
    auto compute = [&](int buf, const short8* bFr) {
      short8 aF[4];
      #pragma unroll
      for (int mi = 0; mi < 4; ++mi)
        aF[mi] = *(const short8*)((const char*)&As[buf][0][0] + ((mi * 16 + fr) * 64 + soff));
      #pragma unroll
      for (int mi = 0; mi < 4; ++mi)
        #pragma unroll
        for (int ni = 0; ni < 4; ++ni)
          acc[mi][ni] = __builtin_amdgcn_mfma_f32_16x16x32_bf16(aF[mi], bFr[ni], acc[mi][ni], 0, 0, 0);
    };

    stageA(0, 0);
    loadB(bF0, 0);
    #pragma unroll 1
    for (int s2 = 0; s2 < 10; ++s2) {
      int se = s2 * 2;                          // even step: As[0], bF0
      stageA(1, (se + 1) * 32);                 // se <= 18 -> always a next step
      loadB(bF1, (se + 1) * 32);
      asm volatile("s_waitcnt vmcnt(8)" ::: "memory");   // step-se's A stage + B regs done
      compute(0, bF0);
      int so = se + 1;                          // odd step: As[1], bF1
      if (so < 19) {
        stageA(0, (so + 1) * 32);
        loadB(bF0, (so + 1) * 32);
        asm volatile("s_waitcnt vmcnt(8)" ::: "memory");
      } else {
        asm volatile("s_waitcnt vmcnt(0)" ::: "memory");
      }
      compute(1, bF1);
    }

    // ---- transition: cost = 1 - sim through TWO 32-row chunks of Cm (8 KB each),
    // overlaying the staging LDS. Single wave: DS pipe in-order; lgkmcnt(0)+sched_barrier
    // pins the write->read and read->overwrite boundaries.
    // C/D layout: acc[mi][ni][r] = C[row = mi*16 + k8*4 + r][col = ni*16 + fr].
    f32x2 EcolP[32], ErowP[32];
    float colsum = 0.f, rowsum = 0.f;
    #pragma unroll
    for (int ch = 0; ch < 2; ++ch) {
      #pragma unroll
      for (int mh = 0; mh < 2; ++mh) {
        int mi = ch * 2 + mh;
        #pragma unroll
        for (int ni = 0; ni < 4; ++ni)
          #pragma unroll
          for (int r = 0; r < 4; ++r) {
            int rr = mh * 16 + k8 * 4 + r;       // local row 0..31
            int col = ni * 16 + fr;
            Cm[rr * 64 + (col ^ SWZ(rr))] = 1.0f - acc[mi][ni][r];
          }
      }
      asm volatile("s_waitcnt lgkmcnt(0)" ::: "memory");
      __builtin_amdgcn_sched_barrier(0);
      // Ecol slice: lane l reads column l of this chunk (l^SWZ permutes within row: 2-way)
      #pragma unroll
      for (int i2 = 0; i2 < 16; ++i2) {
        float c0 = Cm[(2 * i2) * 64 + (l ^ SWZ(2 * i2))];
        float c1 = Cm[(2 * i2 + 1) * 64 + (l ^ SWZ(2 * i2 + 1))];
        colsum += (1.0f - c0);
        colsum += (1.0f - c1);
        EcolP[ch * 16 + i2][0] = __builtin_amdgcn_exp2f(-KC * c0);
        EcolP[ch * 16 + i2][1] = __builtin_amdgcn_exp2f(-KC * c1);
      }
      // Erow slice: the 32 lanes whose row lives in this chunk grab it (f32x4; SWZ is a
      // multiple of 4 words so 16B chunks stay contiguous).
      if ((l >> 5) == ch) {
        int rr = l & 31, sw = SWZ(rr);
        #pragma unroll
        for (int j4 = 0; j4 < 16; ++j4) {
          f32x4 cc = *(const f32x4*)&Cm[rr * 64 + ((j4 * 4) ^ sw)];
          rowsum += cc[0]; rowsum += cc[1]; rowsum += cc[2]; rowsum += cc[3];
          ErowP[j4 * 2][0]     = __builtin_amdgcn_exp2f(-KC * cc[0]);
          ErowP[j4 * 2][1]     = __builtin_amdgcn_exp2f(-KC * cc[1]);
          ErowP[j4 * 2 + 1][0] = __builtin_amdgcn_exp2f(-KC * cc[2]);
          ErowP[j4 * 2 + 1][1] = __builtin_amdgcn_exp2f(-KC * cc[3]);
        }
      }
      asm volatile("s_waitcnt lgkmcnt(0)" ::: "memory");
      __builtin_amdgcn_sched_barrier(0);
    }

    // masses: weight_1 = relu(mean_y sim)+1e-3 (rows), weight_2' = relu(mean_x sim)+1e-3 (cols)
    float w1 = fmaxf(1.0f - rowsum * (1.0f / 64.0f), 0.f) + 0.001f;
    float w2 = fmaxf(colsum * (1.0f / 64.0f), 0.f) + 0.001f;
    float amass = w1 * __builtin_amdgcn_rcpf(wredsum(w1));
    float bmass = w2 * __builtin_amdgcn_rcpf(wredsum(w2));

    const float UMIN = 1.80485139e-35f;   // exp(-80) == exp(-4/eps): the f,g +-4 clamp
    const float UMAX = 5.54062238e+34f;   // exp(+80)

    float uu = 0.f, vv = 1.0f;            // g0 = 0 -> v0 = 1
    float pv = vv;                        // convergence window anchor
    #pragma unroll 1
    for (int it = 0; it < 50; ++it) {
      // u-update: s_l = sum_j Erow[j] * v_j, SGPR-batched broadcast + 4 pk chains
      f32x2 sA0 = {1e-37f, 0.f}, sA1 = {0.f, 0.f}, sA2 = {0.f, 0.f}, sA3 = {0.f, 0.f};
      #pragma unroll
      for (int g = 0; g < 4; ++g) {
        long P[8];
        #pragma unroll
        for (int p = 0; p < 8; ++p) P[p] = pack2(vv, (g * 8 + p) * 2);
        #pragma unroll
        for (int p = 0; p < 8; ++p) {
          if ((p & 3) == 0)      asm("v_pk_fma_f32 %0, %1, %2, %0" : "+v"(sA0) : "v"(ErowP[g * 8 + p]), "s"(P[p]));
          else if ((p & 3) == 1) asm("v_pk_fma_f32 %0, %1, %2, %0" : "+v"(sA1) : "v"(ErowP[g * 8 + p]), "s"(P[p]));
          else if ((p & 3) == 2) asm("v_pk_fma_f32 %0, %1, %2, %0" : "+v"(sA2) : "v"(ErowP[g * 8 + p]), "s"(P[p]));
          else                   asm("v_pk_fma_f32 %0, %1, %2, %0" : "+v"(sA3) : "v"(ErowP[g * 8 + p]), "s"(P[p]));
        }
      }
      float s = ((sA0[0] + sA0[1]) + (sA1[0] + sA1[1])) + ((sA2[0] + sA2[1]) + (sA3[0] + sA3[1]));
      uu = fminf(fmaxf(amass * __builtin_amdgcn_rcpf(s), UMIN), UMAX);

      // v-update: t_l = sum_i Ecol[i] * u_i
      f32x2 tA0 = {1e-37f, 0.f}, tA1 = {0.f, 0.f}, tA2 = {0.f, 0.f}, tA3 = {0.f, 0.f};
      #pragma unroll
      for (int g = 0; g < 4; ++g) {
        long P[8];
        #pragma unroll
        for (int p = 0; p < 8; ++p) P[p] = pack2(uu, (g * 8 + p) * 2);
        #pragma unroll
        for (int p = 0; p < 8; ++p) {
          if ((p & 3) == 0)      asm("v_pk_fma_f32 %0, %1, %2, %0" : "+v"(tA0) : "v"(EcolP[g * 8 + p]), "s"(P[p]));
          else if ((p & 3) == 1) asm("v_pk_fma_f32 %0, %1, %2, %0" : "+v"(tA1) : "v"(EcolP[g * 8 + p]), "s"(P[p]));
          else if ((p & 3) == 2) asm("v_pk_fma_f32 %0, %1, %2, %0" : "+v"(tA2) : "v"(EcolP[g * 8 + p]), "s"(P[p]));
          else                   asm("v_pk_fma_f32 %0, %1, %2, %0" : "+v"(tA3) : "v"(EcolP[g * 8 + p]), "s"(P[p]));
        }
      }
      float t = ((tA0[0] + tA0[1]) + (tA1[0] + tA1[1])) + ((tA2[0] + tA2[1]) + (tA3[0] + tA3[1]));
      vv = fminf(fmaxf(bmass * __builtin_amdgcn_rcpf(t), UMIN), UMAX);

      // fixed-point early-exit: converged-to-1e-6 iterates drift <1e-5 on logits vs iter-50
      if ((it & 1) == 1) {
        if (__all(fabsf(vv - pv) <= 1e-6f * vv)) break;
        pv = vv;
      }
    }

    // logits = 12.5 * sum_ij (1 - c_ij) * u_i v_j E_ij ; recover c = -eps*ln2*log2(E)
    float a1 = 0.f, a2 = 0.f;
    #pragma unroll
    for (int j = 0; j < 64; ++j) {
      float Ej = ErowP[j >> 1][j & 1];
      float e = fminf((uu * Ej) * rl(vv, j), 1.32922800e36f);  // 2^120 guard parity
      float c = -EPSLN2 * __builtin_amdgcn_logf(Ej);
      a1 += e;
      a2 = fmaf(c, e, a2);
    }
    float tot = wredsum(a1 - a2);
    if (l == 0) out[blk] = 12.5f * tot;
  }
}

extern "C" void kernel_launch(void* const* d_in, const int* in_sizes, int n_in,
                              void* d_out, int out_size, void* d_ws, size_t ws_size,
                              hipStream_t stream) {
  const float* query = (const float*)d_in[0];
  const float* proto = (const float*)d_in[1];
  float* out = (float*)d_out;
  char* ws = (char*)d_ws;

  const size_t A_OFF = 0;                  // 8*75*64*640*2  = 49,152,000
  const size_t B_OFF = 49152000;           // 8*5*64*640*2   =  3,276,800
  const size_t C_OFF = 52428800;           // 8 x 16 u32 work-steal counters (512 B)
  if (ws_size < 52429312ull) return;       // loud failure rather than OOB

  unsigned short* Abf = (unsigned short*)(ws + A_OFF);
  unsigned short* Bbf = (unsigned short*)(ws + B_OFF);
  unsigned int* ctr = (unsigned int*)(ws + C_OFF);

  norm_pack<<<640, 1024, 0, stream>>>(query, proto, Abf, Bbf, ctr);  // + counter zeroing
  gemm_sink<<<2048, 64, 0, stream>>>(Abf, Bbf, out, ctr);            // persistent, scalarized stealing
}

// Round 16
// 79.534 us; speedup vs baseline: 1.1165x; 1.0626x over previous
//
#include <hip/hip_runtime.h>
#include <hip/hip_bf16.h>

typedef __attribute__((ext_vector_type(8))) short short8;
typedef __attribute__((ext_vector_type(4))) float f32x4;
typedef __attribute__((ext_vector_type(2))) float f32x2;

#define SEPS   0.05f
#define KC     28.853900817779268f     // log2(e)/eps
#define EPSLN2 0.034657359027997264f   // eps*ln2 = 1/KC
#define LN2    0.6931471805599453f

__device__ __forceinline__ unsigned short bf16_rne(float f) {
  unsigned int u = __float_as_uint(f);
  unsigned int r = (u + 0x7fffu + ((u >> 16) & 1u)) >> 16;
  return (unsigned short)r;
}

// ---------------- K1: per-(b,m) chunk [640 c][64 x] f32 -> l2norm over c -> bf16 [64 x][640 c]
// Single-pass, register-resident; at HBM roofline (~21 us for 153 MB).
__global__ __launch_bounds__(1024) void norm_pack(const float* __restrict__ q,
                                                  const float* __restrict__ p,
                                                  unsigned short* __restrict__ qo,
                                                  unsigned short* __restrict__ po) {
  int blk = blockIdx.x;
  const float* src;
  unsigned short* dst;
  if (blk < 600) { src = q + (size_t)blk * 40960; dst = qo + (size_t)blk * 40960; }
  else           { src = p + (size_t)(blk - 600) * 40960; dst = po + (size_t)(blk - 600) * 40960; }

  int t = threadIdx.x;
  int xg = t & 15, cg = t >> 4;   // xg: x-quad 0..15, cg: c-row 0..63
  int x4 = xg * 4;

  f32x4 v[10];
  float ss[4] = {0.f, 0.f, 0.f, 0.f};
  #pragma unroll
  for (int k = 0; k < 10; ++k) {
    v[k] = *(const f32x4*)(src + (size_t)(cg + 64 * k) * 64 + x4);
    #pragma unroll
    for (int j = 0; j < 4; ++j) ss[j] = fmaf(v[k][j], v[k][j], ss[j]);
  }

  #pragma unroll
  for (int j = 0; j < 4; ++j) {
    ss[j] += __shfl_xor(ss[j], 16, 64);
    ss[j] += __shfl_xor(ss[j], 32, 64);
  }
  __shared__ float red[16][64];
  __shared__ float scale_s[64];
  int wv = t >> 6, ln = t & 63;
  if (ln < 16) {
    #pragma unroll
    for (int j = 0; j < 4; ++j) red[wv][ln * 4 + j] = ss[j];
  }
  __syncthreads();
  if (t < 64) {
    float s = 0.f;
    #pragma unroll
    for (int w2 = 0; w2 < 16; ++w2) s += red[w2][t];
    scale_s[t] = 1.0f / fmaxf(sqrtf(s), 1e-12f);  // matches x/max(||x||,eps)
  }
  __syncthreads();
  float sc[4];
  #pragma unroll
  for (int j = 0; j < 4; ++j) sc[j] = scale_s[x4 + j];

  __shared__ float tile[2][64][65];
  int t9 = t & 511, th = t >> 9;
  int pr = t9 >> 3, pc = (t9 & 7) * 8;
  #pragma unroll
  for (int rd = 0; rd < 5; ++rd) {
    #pragma unroll
    for (int h = 0; h < 2; ++h) {
      f32x4 u = v[rd * 2 + h];
      #pragma unroll
      for (int j = 0; j < 4; ++j) tile[h][x4 + j][cg] = u[j] * sc[j];
    }
    __syncthreads();
    unsigned int pk[4];
    #pragma unroll
    for (int k2 = 0; k2 < 4; ++k2) {
      unsigned int lo = bf16_rne(tile[th][pr][pc + 2 * k2]);
      unsigned int hi = bf16_rne(tile[th][pr][pc + 2 * k2 + 1]);
      pk[k2] = lo | (hi << 16);
    }
    *(uint4*)(dst + (size_t)pr * 640 + (rd * 2 + th) * 64 + pc) = make_uint4(pk[0], pk[1], pk[2], pk[3]);
    __syncthreads();
  }
}

// ---------------- K2: fused per-(b,q,w) {GEMM -> Sinkhorn -> logit}, 8 KB LDS, (64,2).
// Round-12 configuration restored (session best, 79.0 us): static 3000 grid with
// XCD-grouped work = (blk%8)*375 + blk/8 (all 5 blocks sharing an A-tile on one XCD
// -> FETCH 136->26 MB), A staged via global_load_lds double-buffer, B register
// double-buffer, two-chunk cost transpose, pk_fma Sinkhorn with SGPR-batched
// broadcast, early-exit every 2 iters. Persistent/work-steal variants (r14/r15) are
// strictly slower: the 3000/2048 capacity ratio tail is intrinsic, stealing can't
// change it (per-XCD 375/256 = same fraction) and costs +32 VGPR + atomics.
// Only delta vs round-12: epilogue readlanes SGPR-batched (same j-order ->
// bit-identical output; removes the 64-deep readlane->VALU hazard chain).
__device__ __forceinline__ float rl(float v, int lane) {
  return __int_as_float(__builtin_amdgcn_readlane(__float_as_int(v), lane));
}
__device__ __forceinline__ long pack2(float v, int j) {
  unsigned int lo = (unsigned int)__builtin_amdgcn_readlane(__float_as_int(v), j);
  unsigned int hi = (unsigned int)__builtin_amdgcn_readlane(__float_as_int(v), j + 1);
  return (long)(((unsigned long long)hi << 32) | lo);
}
__device__ __forceinline__ float wredsum(float v) {
  #pragma unroll
  for (int m = 1; m < 64; m <<= 1) v += __shfl_xor(v, m, 64);
  return v;
}
#define SWZ(row) ((((row) ^ ((row) >> 3)) & 15) << 2)

__global__ __launch_bounds__(64, 2) void gemm_sink(const unsigned short* __restrict__ A,
                                                   const unsigned short* __restrict__ B,
                                                   float* __restrict__ out) {
  __shared__ alignas(16) char sh[8192];
  unsigned short (*As)[64][32] = (unsigned short (*)[64][32])sh;  // [2][64][32] = 8 KB
  float* Cm = (float*)sh;  // 2048 f32 = one 32-row chunk, reused after GEMM phase

  int blk0 = blockIdx.x;
  int blk = (blk0 & 7) * 375 + (blk0 >> 3);  // XCD-grouped (8 XCDs x 375 works, bijective)
  int w = blk % 5;
  int bq = blk / 5;
  int b = bq / 75;
  const unsigned short* Ab = A + (size_t)bq * 40960;
  const unsigned short* Bb = B + (size_t)(b * 5 + w) * 40960;

  int l = threadIdx.x;
  int lrow = l >> 2, lslot = l & 3;
  int fr = l & 15, k8 = l >> 4;
  int soff = ((k8 ^ (fr & 3)) << 4);  // swizzled 16B slot byte offset within 64B row

  f32x4 acc[4][4];
  #pragma unroll
  for (int i = 0; i < 4; ++i)
    #pragma unroll
    for (int j = 0; j < 4; ++j)
      acc[i][j] = (f32x4){0.f, 0.f, 0.f, 0.f};

  auto stageA = [&](int buf, int k0) {
    #pragma unroll
    for (int t = 0; t < 4; ++t) {
      int row = t * 16 + lrow;
      int sl = lslot ^ (row & 3);
      __builtin_amdgcn_global_load_lds(
          (const __attribute__((address_space(1))) unsigned int*)(Ab + (size_t)row * 640 + k0 + sl * 8),
          (__attribute__((address_space(3))) unsigned int*)&As[buf][t * 16][0], 16, 0, 0);
    }
  };
  short8 bF0[4], bF1[4];
  auto loadB = [&](short8* dst, int k0) {
    #pragma unroll
    for (int mi = 0; mi < 4; ++mi)
      dst[mi] = *(const short8*)(Bb + (size_t)(mi * 16 + fr) * 640 + k0 + k8 * 8);
  };
  auto compute = [&](int buf, const short8* bFr) {
    short8 aF[4];
    #pragma unroll
    for (int mi = 0; mi < 4; ++mi)
      aF[mi] = *(const short8*)((const char*)&As[buf][0][0] + ((mi * 16 + fr) * 64 + soff));
    #pragma unroll
    for (int mi = 0; mi < 4; ++mi)
      #pragma unroll
      for (int ni = 0; ni < 4; ++ni)
        acc[mi][ni] = __builtin_amdgcn_mfma_f32_16x16x32_bf16(aF[mi], bFr[ni], acc[mi][ni], 0, 0, 0);
  };

  stageA(0, 0);
  loadB(bF0, 0);
  #pragma unroll 1
  for (int s2 = 0; s2 < 10; ++s2) {
    int se = s2 * 2;                          // even step: As[0], bF0
    stageA(1, (se + 1) * 32);                 // se <= 18 -> always a next step
    loadB(bF1, (se + 1) * 32);
    asm volatile("s_waitcnt vmcnt(8)" ::: "memory");   // step-se's A stage + B regs done
    compute(0, bF0);
    int so = se + 1;                          // odd step: As[1], bF1
    if (so < 19) {
      stageA(0, (so + 1) * 32);
      loadB(bF0, (so + 1) * 32);
      asm volatile("s_waitcnt vmcnt(8)" ::: "memory");
    } else {
      asm volatile("s_waitcnt vmcnt(0)" ::: "memory");
    }
    compute(1, bF1);
  }

  // ---- transition: cost = 1 - sim through TWO 32-row chunks of Cm (8 KB each),
  // overlaying the staging LDS. Single wave: DS pipe in-order; lgkmcnt(0)+sched_barrier
  // pins the write->read and read->overwrite boundaries.
  // C/D layout: acc[mi][ni][r] = C[row = mi*16 + k8*4 + r][col = ni*16 + fr].
  f32x2 EcolP[32], ErowP[32];
  float colsum = 0.f, rowsum = 0.f;
  #pragma unroll
  for (int ch = 0; ch < 2; ++ch) {
    #pragma unroll
    for (int mh = 0; mh < 2; ++mh) {
      int mi = ch * 2 + mh;
      #pragma unroll
      for (int ni = 0; ni < 4; ++ni)
        #pragma unroll
        for (int r = 0; r < 4; ++r) {
          int rr = mh * 16 + k8 * 4 + r;       // local row 0..31
          int col = ni * 16 + fr;
          Cm[rr * 64 + (col ^ SWZ(rr))] = 1.0f - acc[mi][ni][r];
        }
    }
    asm volatile("s_waitcnt lgkmcnt(0)" ::: "memory");
    __builtin_amdgcn_sched_barrier(0);
    // Ecol slice: lane l reads column l of this chunk (l^SWZ permutes within row: 2-way)
    #pragma unroll
    for (int i2 = 0; i2 < 16; ++i2) {
      float c0 = Cm[(2 * i2) * 64 + (l ^ SWZ(2 * i2))];
      float c1 = Cm[(2 * i2 + 1) * 64 + (l ^ SWZ(2 * i2 + 1))];
      colsum += (1.0f - c0);
      colsum += (1.0f - c1);
      EcolP[ch * 16 + i2][0] = __builtin_amdgcn_exp2f(-KC * c0);
      EcolP[ch * 16 + i2][1] = __builtin_amdgcn_exp2f(-KC * c1);
    }
    // Erow slice: the 32 lanes whose row lives in this chunk grab it (f32x4; SWZ is a
    // multiple of 4 words so 16B chunks stay contiguous).
    if ((l >> 5) == ch) {
      int rr = l & 31, sw = SWZ(rr);
      #pragma unroll
      for (int j4 = 0; j4 < 16; ++j4) {
        f32x4 cc = *(const f32x4*)&Cm[rr * 64 + ((j4 * 4) ^ sw)];
        rowsum += cc[0]; rowsum += cc[1]; rowsum += cc[2]; rowsum += cc[3];
        ErowP[j4 * 2][0]     = __builtin_amdgcn_exp2f(-KC * cc[0]);
        ErowP[j4 * 2][1]     = __builtin_amdgcn_exp2f(-KC * cc[1]);
        ErowP[j4 * 2 + 1][0] = __builtin_amdgcn_exp2f(-KC * cc[2]);
        ErowP[j4 * 2 + 1][1] = __builtin_amdgcn_exp2f(-KC * cc[3]);
      }
    }
    asm volatile("s_waitcnt lgkmcnt(0)" ::: "memory");
    __builtin_amdgcn_sched_barrier(0);
  }

  // masses: weight_1 = relu(mean_y sim)+1e-3 (rows), weight_2' = relu(mean_x sim)+1e-3 (cols)
  float w1 = fmaxf(1.0f - rowsum * (1.0f / 64.0f), 0.f) + 0.001f;
  float w2 = fmaxf(colsum * (1.0f / 64.0f), 0.f) + 0.001f;
  float amass = w1 * __builtin_amdgcn_rcpf(wredsum(w1));
  float bmass = w2 * __builtin_amdgcn_rcpf(wredsum(w2));

  const float UMIN = 1.80485139e-35f;   // exp(-80) == exp(-4/eps): the f,g +-4 clamp
  const float UMAX = 5.54062238e+34f;   // exp(+80)

  float uu = 0.f, vv = 1.0f;            // g0 = 0 -> v0 = 1
  float pv = vv;                        // convergence window anchor
  #pragma unroll 1
  for (int it = 0; it < 50; ++it) {
    // u-update: s_l = sum_j Erow[j] * v_j, SGPR-batched broadcast + 4 pk chains
    f32x2 sA0 = {1e-37f, 0.f}, sA1 = {0.f, 0.f}, sA2 = {0.f, 0.f}, sA3 = {0.f, 0.f};
    #pragma unroll
    for (int g = 0; g < 4; ++g) {
      long P[8];
      #pragma unroll
      for (int p = 0; p < 8; ++p) P[p] = pack2(vv, (g * 8 + p) * 2);
      #pragma unroll
      for (int p = 0; p < 8; ++p) {
        if ((p & 3) == 0)      asm("v_pk_fma_f32 %0, %1, %2, %0" : "+v"(sA0) : "v"(ErowP[g * 8 + p]), "s"(P[p]));
        else if ((p & 3) == 1) asm("v_pk_fma_f32 %0, %1, %2, %0" : "+v"(sA1) : "v"(ErowP[g * 8 + p]), "s"(P[p]));
        else if ((p & 3) == 2) asm("v_pk_fma_f32 %0, %1, %2, %0" : "+v"(sA2) : "v"(ErowP[g * 8 + p]), "s"(P[p]));
        else                   asm("v_pk_fma_f32 %0, %1, %2, %0" : "+v"(sA3) : "v"(ErowP[g * 8 + p]), "s"(P[p]));
      }
    }
    float s = ((sA0[0] + sA0[1]) + (sA1[0] + sA1[1])) + ((sA2[0] + sA2[1]) + (sA3[0] + sA3[1]));
    uu = fminf(fmaxf(amass * __builtin_amdgcn_rcpf(s), UMIN), UMAX);

    // v-update: t_l = sum_i Ecol[i] * u_i
    f32x2 tA0 = {1e-37f, 0.f}, tA1 = {0.f, 0.f}, tA2 = {0.f, 0.f}, tA3 = {0.f, 0.f};
    #pragma unroll
    for (int g = 0; g < 4; ++g) {
      long P[8];
      #pragma unroll
      for (int p = 0; p < 8; ++p) P[p] = pack2(uu, (g * 8 + p) * 2);
      #pragma unroll
      for (int p = 0; p < 8; ++p) {
        if ((p & 3) == 0)      asm("v_pk_fma_f32 %0, %1, %2, %0" : "+v"(tA0) : "v"(EcolP[g * 8 + p]), "s"(P[p]));
        else if ((p & 3) == 1) asm("v_pk_fma_f32 %0, %1, %2, %0" : "+v"(tA1) : "v"(EcolP[g * 8 + p]), "s"(P[p]));
        else if ((p & 3) == 2) asm("v_pk_fma_f32 %0, %1, %2, %0" : "+v"(tA2) : "v"(EcolP[g * 8 + p]), "s"(P[p]));
        else                   asm("v_pk_fma_f32 %0, %1, %2, %0" : "+v"(tA3) : "v"(EcolP[g * 8 + p]), "s"(P[p]));
      }
    }
    float t = ((tA0[0] + tA0[1]) + (tA1[0] + tA1[1])) + ((tA2[0] + tA2[1]) + (tA3[0] + tA3[1]));
    vv = fminf(fmaxf(bmass * __builtin_amdgcn_rcpf(t), UMIN), UMAX);

    // fixed-point early-exit: converged-to-1e-6 iterates drift <1e-5 on logits vs iter-50
    if ((it & 1) == 1) {
      if (__all(fabsf(vv - pv) <= 1e-6f * vv)) break;
      pv = vv;
    }
  }

  // logits = 12.5 * sum_ij (1 - c_ij) * u_i v_j E_ij ; recover c = -eps*ln2*log2(E)
  // readlanes SGPR-batched in groups of 8 (same j-order as round-12 -> bit-identical)
  float a1 = 0.f, a2 = 0.f;
  #pragma unroll
  for (int g = 0; g < 8; ++g) {
    float vj[8];
    #pragma unroll
    for (int p = 0; p < 8; ++p) vj[p] = rl(vv, g * 8 + p);
    #pragma unroll
    for (int p = 0; p < 8; ++p) {
      int j = g * 8 + p;
      float Ej = ErowP[j >> 1][j & 1];
      float e = fminf((uu * Ej) * vj[p], 1.32922800e36f);  // 2^120 guard parity
      float c = -EPSLN2 * __builtin_amdgcn_logf(Ej);
      a1 += e;
      a2 = fmaf(c, e, a2);
    }
  }
  float tot = wredsum(a1 - a2);
  if (l == 0) out[blk] = 12.5f * tot;
}

extern "C" void kernel_launch(void* const* d_in, const int* in_sizes, int n_in,
                              void* d_out, int out_size, void* d_ws, size_t ws_size,
                              hipStream_t stream) {
  const float* query = (const float*)d_in[0];
  const float* proto = (const float*)d_in[1];
  float* out = (float*)d_out;
  char* ws = (char*)d_ws;

  const size_t A_OFF = 0;                  // 8*75*64*640*2  = 49,152,000
  const size_t B_OFF = 49152000;           // 8*5*64*640*2   =  3,276,800
  if (ws_size < 52428800ull) return;       // loud failure rather than OOB

  unsigned short* Abf = (unsigned short*)(ws + A_OFF);
  unsigned short* Bbf = (unsigned short*)(ws + B_OFF);

  norm_pack<<<640, 1024, 0, stream>>>(query, proto, Abf, Bbf);  // 600 query + 40 proto chunks
  gemm_sink<<<3000, 64, 0, stream>>>(Abf, Bbf, out);            // fused GEMM + Sinkhorn
}

// Round 17
// 77.235 us; speedup vs baseline: 1.1497x; 1.0298x over previous
//
#include <hip/hip_runtime.h>
#include <hip/hip_bf16.h>

typedef __attribute__((ext_vector_type(8))) short short8;
typedef __attribute__((ext_vector_type(4))) float f32x4;
typedef __attribute__((ext_vector_type(2))) float f32x2;

#define SEPS   0.05f
#define KC     28.853900817779268f     // log2(e)/eps
#define EPSLN2 0.034657359027997264f   // eps*ln2 = 1/KC
#define LN2    0.6931471805599453f

__device__ __forceinline__ unsigned short bf16_rne(float f) {
  unsigned int u = __float_as_uint(f);
  unsigned int r = (u + 0x7fffu + ((u >> 16) & 1u)) >> 16;
  return (unsigned short)r;
}

// ---------------- K1: per-(b,m) chunk [640 c][64 x] f32 -> l2norm over c -> bf16 [64 x][640 c]
// Single-pass, register-resident; at HBM roofline (~21 us for 153 MB).
__global__ __launch_bounds__(1024) void norm_pack(const float* __restrict__ q,
                                                  const float* __restrict__ p,
                                                  unsigned short* __restrict__ qo,
                                                  unsigned short* __restrict__ po) {
  int blk = blockIdx.x;
  const float* src;
  unsigned short* dst;
  if (blk < 600) { src = q + (size_t)blk * 40960; dst = qo + (size_t)blk * 40960; }
  else           { src = p + (size_t)(blk - 600) * 40960; dst = po + (size_t)(blk - 600) * 40960; }

  int t = threadIdx.x;
  int xg = t & 15, cg = t >> 4;   // xg: x-quad 0..15, cg: c-row 0..63
  int x4 = xg * 4;

  f32x4 v[10];
  float ss[4] = {0.f, 0.f, 0.f, 0.f};
  #pragma unroll
  for (int k = 0; k < 10; ++k) {
    v[k] = *(const f32x4*)(src + (size_t)(cg + 64 * k) * 64 + x4);
    #pragma unroll
    for (int j = 0; j < 4; ++j) ss[j] = fmaf(v[k][j], v[k][j], ss[j]);
  }

  #pragma unroll
  for (int j = 0; j < 4; ++j) {
    ss[j] += __shfl_xor(ss[j], 16, 64);
    ss[j] += __shfl_xor(ss[j], 32, 64);
  }
  __shared__ float red[16][64];
  __shared__ float scale_s[64];
  int wv = t >> 6, ln = t & 63;
  if (ln < 16) {
    #pragma unroll
    for (int j = 0; j < 4; ++j) red[wv][ln * 4 + j] = ss[j];
  }
  __syncthreads();
  if (t < 64) {
    float s = 0.f;
    #pragma unroll
    for (int w2 = 0; w2 < 16; ++w2) s += red[w2][t];
    scale_s[t] = 1.0f / fmaxf(sqrtf(s), 1e-12f);  // matches x/max(||x||,eps)
  }
  __syncthreads();
  float sc[4];
  #pragma unroll
  for (int j = 0; j < 4; ++j) sc[j] = scale_s[x4 + j];

  __shared__ float tile[2][64][65];
  int t9 = t & 511, th = t >> 9;
  int pr = t9 >> 3, pc = (t9 & 7) * 8;
  #pragma unroll
  for (int rd = 0; rd < 5; ++rd) {
    #pragma unroll
    for (int h = 0; h < 2; ++h) {
      f32x4 u = v[rd * 2 + h];
      #pragma unroll
      for (int j = 0; j < 4; ++j) tile[h][x4 + j][cg] = u[j] * sc[j];
    }
    __syncthreads();
    unsigned int pk[4];
    #pragma unroll
    for (int k2 = 0; k2 < 4; ++k2) {
      unsigned int lo = bf16_rne(tile[th][pr][pc + 2 * k2]);
      unsigned int hi = bf16_rne(tile[th][pr][pc + 2 * k2 + 1]);
      pk[k2] = lo | (hi << 16);
    }
    *(uint4*)(dst + (size_t)pr * 640 + (rd * 2 + th) * 64 + pc) = make_uint4(pk[0], pk[1], pk[2], pk[3]);
    __syncthreads();
  }
}

// ---------------- K2: fused per-(b,q,w) {GEMM -> Sinkhorn -> logit}, 8 KB LDS, (64,2).
// Round-16 base (session best 79.0-79.5 us): static 3000 grid, XCD-grouped work
// (FETCH 136->26 MB), A via global_load_lds double-buffer, B register double-buffer,
// two-chunk cost transpose, pk_fma Sinkhorn with SGPR-batched broadcast.
// Only delta vs round-16: early-exit tightened in TIME, loosened in TOL -- check
// EVERY iteration at rel-tol 1e-5 (was every-2 at 1e-6). Residual v-error at exit
// ~ tol*kappa/(1-kappa) ~ 1.2e-5 -> logit drift ~2e-5, three orders below the
// bf16-GEMM-dominated 0.0039 absmax. Saves ~4-5 of ~15 iterations.
__device__ __forceinline__ float rl(float v, int lane) {
  return __int_as_float(__builtin_amdgcn_readlane(__float_as_int(v), lane));
}
__device__ __forceinline__ long pack2(float v, int j) {
  unsigned int lo = (unsigned int)__builtin_amdgcn_readlane(__float_as_int(v), j);
  unsigned int hi = (unsigned int)__builtin_amdgcn_readlane(__float_as_int(v), j + 1);
  return (long)(((unsigned long long)hi << 32) | lo);
}
__device__ __forceinline__ float wredsum(float v) {
  #pragma unroll
  for (int m = 1; m < 64; m <<= 1) v += __shfl_xor(v, m, 64);
  return v;
}
#define SWZ(row) ((((row) ^ ((row) >> 3)) & 15) << 2)

__global__ __launch_bounds__(64, 2) void gemm_sink(const unsigned short* __restrict__ A,
                                                   const unsigned short* __restrict__ B,
                                                   float* __restrict__ out) {
  __shared__ alignas(16) char sh[8192];
  unsigned short (*As)[64][32] = (unsigned short (*)[64][32])sh;  // [2][64][32] = 8 KB
  float* Cm = (float*)sh;  // 2048 f32 = one 32-row chunk, reused after GEMM phase

  int blk0 = blockIdx.x;
  int blk = (blk0 & 7) * 375 + (blk0 >> 3);  // XCD-grouped (8 XCDs x 375 works, bijective)
  int w = blk % 5;
  int bq = blk / 5;
  int b = bq / 75;
  const unsigned short* Ab = A + (size_t)bq * 40960;
  const unsigned short* Bb = B + (size_t)(b * 5 + w) * 40960;

  int l = threadIdx.x;
  int lrow = l >> 2, lslot = l & 3;
  int fr = l & 15, k8 = l >> 4;
  int soff = ((k8 ^ (fr & 3)) << 4);  // swizzled 16B slot byte offset within 64B row

  f32x4 acc[4][4];
  #pragma unroll
  for (int i = 0; i < 4; ++i)
    #pragma unroll
    for (int j = 0; j < 4; ++j)
      acc[i][j] = (f32x4){0.f, 0.f, 0.f, 0.f};

  auto stageA = [&](int buf, int k0) {
    #pragma unroll
    for (int t = 0; t < 4; ++t) {
      int row = t * 16 + lrow;
      int sl = lslot ^ (row & 3);
      __builtin_amdgcn_global_load_lds(
          (const __attribute__((address_space(1))) unsigned int*)(Ab + (size_t)row * 640 + k0 + sl * 8),
          (__attribute__((address_space(3))) unsigned int*)&As[buf][t * 16][0], 16, 0, 0);
    }
  };
  short8 bF0[4], bF1[4];
  auto loadB = [&](short8* dst, int k0) {
    #pragma unroll
    for (int mi = 0; mi < 4; ++mi)
      dst[mi] = *(const short8*)(Bb + (size_t)(mi * 16 + fr) * 640 + k0 + k8 * 8);
  };
  auto compute = [&](int buf, const short8* bFr) {
    short8 aF[4];
    #pragma unroll
    for (int mi = 0; mi < 4; ++mi)
      aF[mi] = *(const short8*)((const char*)&As[buf][0][0] + ((mi * 16 + fr) * 64 + soff));
    #pragma unroll
    for (int mi = 0; mi < 4; ++mi)
      #pragma unroll
      for (int ni = 0; ni < 4; ++ni)
        acc[mi][ni] = __builtin_amdgcn_mfma_f32_16x16x32_bf16(aF[mi], bFr[ni], acc[mi][ni], 0, 0, 0);
  };

  stageA(0, 0);
  loadB(bF0, 0);
  #pragma unroll 1
  for (int s2 = 0; s2 < 10; ++s2) {
    int se = s2 * 2;                          // even step: As[0], bF0
    stageA(1, (se + 1) * 32);                 // se <= 18 -> always a next step
    loadB(bF1, (se + 1) * 32);
    asm volatile("s_waitcnt vmcnt(8)" ::: "memory");   // step-se's A stage + B regs done
    compute(0, bF0);
    int so = se + 1;                          // odd step: As[1], bF1
    if (so < 19) {
      stageA(0, (so + 1) * 32);
      loadB(bF0, (so + 1) * 32);
      asm volatile("s_waitcnt vmcnt(8)" ::: "memory");
    } else {
      asm volatile("s_waitcnt vmcnt(0)" ::: "memory");
    }
    compute(1, bF1);
  }

  // ---- transition: cost = 1 - sim through TWO 32-row chunks of Cm (8 KB each),
  // overlaying the staging LDS. Single wave: DS pipe in-order; lgkmcnt(0)+sched_barrier
  // pins the write->read and read->overwrite boundaries.
  // C/D layout: acc[mi][ni][r] = C[row = mi*16 + k8*4 + r][col = ni*16 + fr].
  f32x2 EcolP[32], ErowP[32];
  float colsum = 0.f, rowsum = 0.f;
  #pragma unroll
  for (int ch = 0; ch < 2; ++ch) {
    #pragma unroll
    for (int mh = 0; mh < 2; ++mh) {
      int mi = ch * 2 + mh;
      #pragma unroll
      for (int ni = 0; ni < 4; ++ni)
        #pragma unroll
        for (int r = 0; r < 4; ++r) {
          int rr = mh * 16 + k8 * 4 + r;       // local row 0..31
          int col = ni * 16 + fr;
          Cm[rr * 64 + (col ^ SWZ(rr))] = 1.0f - acc[mi][ni][r];
        }
    }
    asm volatile("s_waitcnt lgkmcnt(0)" ::: "memory");
    __builtin_amdgcn_sched_barrier(0);
    // Ecol slice: lane l reads column l of this chunk (l^SWZ permutes within row: 2-way)
    #pragma unroll
    for (int i2 = 0; i2 < 16; ++i2) {
      float c0 = Cm[(2 * i2) * 64 + (l ^ SWZ(2 * i2))];
      float c1 = Cm[(2 * i2 + 1) * 64 + (l ^ SWZ(2 * i2 + 1))];
      colsum += (1.0f - c0);
      colsum += (1.0f - c1);
      EcolP[ch * 16 + i2][0] = __builtin_amdgcn_exp2f(-KC * c0);
      EcolP[ch * 16 + i2][1] = __builtin_amdgcn_exp2f(-KC * c1);
    }
    // Erow slice: the 32 lanes whose row lives in this chunk grab it (f32x4; SWZ is a
    // multiple of 4 words so 16B chunks stay contiguous).
    if ((l >> 5) == ch) {
      int rr = l & 31, sw = SWZ(rr);
      #pragma unroll
      for (int j4 = 0; j4 < 16; ++j4) {
        f32x4 cc = *(const f32x4*)&Cm[rr * 64 + ((j4 * 4) ^ sw)];
        rowsum += cc[0]; rowsum += cc[1]; rowsum += cc[2]; rowsum += cc[3];
        ErowP[j4 * 2][0]     = __builtin_amdgcn_exp2f(-KC * cc[0]);
        ErowP[j4 * 2][1]     = __builtin_amdgcn_exp2f(-KC * cc[1]);
        ErowP[j4 * 2 + 1][0] = __builtin_amdgcn_exp2f(-KC * cc[2]);
        ErowP[j4 * 2 + 1][1] = __builtin_amdgcn_exp2f(-KC * cc[3]);
      }
    }
    asm volatile("s_waitcnt lgkmcnt(0)" ::: "memory");
    __builtin_amdgcn_sched_barrier(0);
  }

  // masses: weight_1 = relu(mean_y sim)+1e-3 (rows), weight_2' = relu(mean_x sim)+1e-3 (cols)
  float w1 = fmaxf(1.0f - rowsum * (1.0f / 64.0f), 0.f) + 0.001f;
  float w2 = fmaxf(colsum * (1.0f / 64.0f), 0.f) + 0.001f;
  float amass = w1 * __builtin_amdgcn_rcpf(wredsum(w1));
  float bmass = w2 * __builtin_amdgcn_rcpf(wredsum(w2));

  const float UMIN = 1.80485139e-35f;   // exp(-80) == exp(-4/eps): the f,g +-4 clamp
  const float UMAX = 5.54062238e+34f;   // exp(+80)

  float uu = 0.f, vv = 1.0f;            // g0 = 0 -> v0 = 1
  float pv = vv;                        // convergence anchor (previous iterate)
  #pragma unroll 1
  for (int it = 0; it < 50; ++it) {
    // u-update: s_l = sum_j Erow[j] * v_j, SGPR-batched broadcast + 4 pk chains
    f32x2 sA0 = {1e-37f, 0.f}, sA1 = {0.f, 0.f}, sA2 = {0.f, 0.f}, sA3 = {0.f, 0.f};
    #pragma unroll
    for (int g = 0; g < 4; ++g) {
      long P[8];
      #pragma unroll
      for (int p = 0; p < 8; ++p) P[p] = pack2(vv, (g * 8 + p) * 2);
      #pragma unroll
      for (int p = 0; p < 8; ++p) {
        if ((p & 3) == 0)      asm("v_pk_fma_f32 %0, %1, %2, %0" : "+v"(sA0) : "v"(ErowP[g * 8 + p]), "s"(P[p]));
        else if ((p & 3) == 1) asm("v_pk_fma_f32 %0, %1, %2, %0" : "+v"(sA1) : "v"(ErowP[g * 8 + p]), "s"(P[p]));
        else if ((p & 3) == 2) asm("v_pk_fma_f32 %0, %1, %2, %0" : "+v"(sA2) : "v"(ErowP[g * 8 + p]), "s"(P[p]));
        else                   asm("v_pk_fma_f32 %0, %1, %2, %0" : "+v"(sA3) : "v"(ErowP[g * 8 + p]), "s"(P[p]));
      }
    }
    float s = ((sA0[0] + sA0[1]) + (sA1[0] + sA1[1])) + ((sA2[0] + sA2[1]) + (sA3[0] + sA3[1]));
    uu = fminf(fmaxf(amass * __builtin_amdgcn_rcpf(s), UMIN), UMAX);

    // v-update: t_l = sum_i Ecol[i] * u_i
    f32x2 tA0 = {1e-37f, 0.f}, tA1 = {0.f, 0.f}, tA2 = {0.f, 0.f}, tA3 = {0.f, 0.f};
    #pragma unroll
    for (int g = 0; g < 4; ++g) {
      long P[8];
      #pragma unroll
      for (int p = 0; p < 8; ++p) P[p] = pack2(uu, (g * 8 + p) * 2);
      #pragma unroll
      for (int p = 0; p < 8; ++p) {
        if ((p & 3) == 0)      asm("v_pk_fma_f32 %0, %1, %2, %0" : "+v"(tA0) : "v"(EcolP[g * 8 + p]), "s"(P[p]));
        else if ((p & 3) == 1) asm("v_pk_fma_f32 %0, %1, %2, %0" : "+v"(tA1) : "v"(EcolP[g * 8 + p]), "s"(P[p]));
        else if ((p & 3) == 2) asm("v_pk_fma_f32 %0, %1, %2, %0" : "+v"(tA2) : "v"(EcolP[g * 8 + p]), "s"(P[p]));
        else                   asm("v_pk_fma_f32 %0, %1, %2, %0" : "+v"(tA3) : "v"(EcolP[g * 8 + p]), "s"(P[p]));
      }
    }
    float t = ((tA0[0] + tA0[1]) + (tA1[0] + tA1[1])) + ((tA2[0] + tA2[1]) + (tA3[0] + tA3[1]));
    vv = fminf(fmaxf(bmass * __builtin_amdgcn_rcpf(t), UMIN), UMAX);

    // fixed-point early-exit, per-iteration: residual at exit ~ 1.2*tol (kappa~0.55)
    // -> logit drift ~2e-5, far below the bf16-GEMM-dominated 0.0039 absmax.
    if (__all(fabsf(vv - pv) <= 1e-5f * vv)) break;
    pv = vv;
  }

  // logits = 12.5 * sum_ij (1 - c_ij) * u_i v_j E_ij ; recover c = -eps*ln2*log2(E)
  // readlanes SGPR-batched in groups of 8 (same j-order -> bit-identical)
  float a1 = 0.f, a2 = 0.f;
  #pragma unroll
  for (int g = 0; g < 8; ++g) {
    float vj[8];
    #pragma unroll
    for (int p = 0; p < 8; ++p) vj[p] = rl(vv, g * 8 + p);
    #pragma unroll
    for (int p = 0; p < 8; ++p) {
      int j = g * 8 + p;
      float Ej = ErowP[j >> 1][j & 1];
      float e = fminf((uu * Ej) * vj[p], 1.32922800e36f);  // 2^120 guard parity
      float c = -EPSLN2 * __builtin_amdgcn_logf(Ej);
      a1 += e;
      a2 = fmaf(c, e, a2);
    }
  }
  float tot = wredsum(a1 - a2);
  if (l == 0) out[blk] = 12.5f * tot;
}

extern "C" void kernel_launch(void* const* d_in, const int* in_sizes, int n_in,
                              void* d_out, int out_size, void* d_ws, size_t ws_size,
                              hipStream_t stream) {
  const float* query = (const float*)d_in[0];
  const float* proto = (const float*)d_in[1];
  float* out = (float*)d_out;
  char* ws = (char*)d_ws;

  const size_t A_OFF = 0;                  // 8*75*64*640*2  = 49,152,000
  const size_t B_OFF = 49152000;           // 8*5*64*640*2   =  3,276,800
  if (ws_size < 52428800ull) return;       // loud failure rather than OOB

  unsigned short* Abf = (unsigned short*)(ws + A_OFF);
  unsigned short* Bbf = (unsigned short*)(ws + B_OFF);

  norm_pack<<<640, 1024, 0, stream>>>(query, proto, Abf, Bbf);  // 600 query + 40 proto chunks
  gemm_sink<<<3000, 64, 0, stream>>>(Abf, Bbf, out);            // fused GEMM + Sinkhorn
}